// Round 8
// baseline (113.903 us; speedup 1.0000x reference)
//
#include <hip/hip_runtime.h>
#include <math.h>

#define BDIM 512
#define IDIM 256
#define ODIM 512

// 16B table entry: correctly-rounded fp64 reciprocal of den + the comp value.
struct __align__(16) XT { double r; float c; float pad; };

// jnp.minimum(q, 1.0): NaN-propagating min with 1.0
__device__ __forceinline__ float np_min1(float q) {
    float m = fminf(q, 1.0f);
    return (q != q) ? q : m;
}

// np.argmin update: strict < (first occurrence wins), NaN-first & sticky.
__device__ __forceinline__ bool np_argmin_better(float s, float best) {
    return (s < best) || (isnan(s) && !isnan(best));
}

// Correctly-rounded fp32 divide num/den as RN32(num * r), r = RN64(1/den).
// (no fp32/fp32 quotient is a 25-bit midpoint -> exclusion >= 2^-49 >> 2^-51.9
// rel err; den==0 -> r=+INF -> IEEE num/0.) Bit-stable since R2 (absmax pinned).
__device__ __forceinline__ float q32(float num, double r) {
    return (float)((double)num * r);
}

// async global->LDS, 16B/lane; LDS dest = wave-uniform base + lane*16.
typedef const __attribute__((address_space(1))) unsigned int* gu32p;
typedef __attribute__((address_space(3))) unsigned int* lu32p;
__device__ __forceinline__ void async_cp16(const float* g, float* l) {
    __builtin_amdgcn_global_load_lds((gu32p)(const void*)g, (lu32p)(void*)l, 16, 0, 0);
}

// K1: rel_x[i, o-half] = 1 - S/D, sequential-in-b (numpy order).
// Grid 512 = (i, oh), 256 thr. Triple-buffered t stream, ONE barrier/chunk,
// counted vmcnt (4 in flight mid-loop, never 0).
#define XCH 16
#define XNC (BDIM / XCH)   // 32
__global__ __launch_bounds__(256) void relx_kernel(const float* __restrict__ x,
                                                   const float* __restrict__ t,
                                                   float* __restrict__ relx) {
    __shared__ float tbuf[3][XCH * 256];     // 48 KB
    __shared__ XT    xtab[BDIM];             // 8 KB -> 56 KB, 2 blocks/CU
    const int tid = threadIdx.x;             // o within half: 0..255
    const int i   = blockIdx.x >> 1;         // 0..255
    const int obase = (blockIdx.x & 1) * 256;
    const int l = tid & 63, wv = tid >> 6;   // 4 waves

    // build x-table: one fp64 divide per (b,i), 2 per thread, no chains
    for (int b = tid; b < BDIM; b += 256) {
        float xv  = x[(size_t)b * IDIM + i]; // strided gather, once
        float xc  = __fsub_rn(1.0f, xv);     // x_comp
        float den = __fsub_rn(1.0f, xc);     // NOT simply xv (rounding!)
        XT e; e.r = 1.0 / (double)den; e.c = xc; e.pad = 0.0f;
        xtab[b] = e;                         // den==0 -> r=+INF (IEEE)
    }
    asm volatile("s_waitcnt vmcnt(0)" ::: "memory");  // clean slate for counting
    {   // issue chunks 0,1: wave wv stages rows wv*4..wv*4+3
        const float* g0 = t + (size_t)(wv * 4) * ODIM + obase + l * 4;
        float* l0 = &tbuf[0][(wv * 4) * 256 + l * 4];
        #pragma unroll
        for (int rr = 0; rr < 4; ++rr) async_cp16(g0 + rr * ODIM, l0 + rr * 256);
        const float* g1 = t + (size_t)(XCH + wv * 4) * ODIM + obase + l * 4;
        float* l1 = &tbuf[1][(wv * 4) * 256 + l * 4];
        #pragma unroll
        for (int rr = 0; rr < 4; ++rr) async_cp16(g1 + rr * ODIM, l1 + rr * 256);
    }
    asm volatile("s_waitcnt lgkmcnt(0)" ::: "memory");  // xtab ds_writes done
    __builtin_amdgcn_s_barrier();                       // xtab visible

    float S = 0.0f, D = 0.0f;
    for (int c = 0; c < XNC; ++c) {
        // outstanding: chunk c (4) + chunk c+1 (4, unless last) -> keep 4
        if (c == XNC - 1) asm volatile("s_waitcnt vmcnt(0)" ::: "memory");
        else              asm volatile("s_waitcnt vmcnt(4)" ::: "memory");
        __builtin_amdgcn_s_barrier();        // everyone's chunk-c loads landed
        asm volatile("" ::: "memory");
        const float* tb = tbuf[c % 3];
        #pragma unroll
        for (int u = 0; u < XCH; ++u) {
            float tv = tb[u * 256 + tid];    // conflict-free
            XT e = xtab[c * XCH + u];        // uniform broadcast b128
            float tc  = __fsub_rn(1.0f, tv); // t_comp
            float num = __fsub_rn(tc, e.c);
            float q   = np_min1(q32(num, e.r));
            S = __fadd_rn(S, q);             // exact sequential order
            D = __fadd_rn(D, e.c);
        }
        asm volatile("" ::: "memory");
        if (c + 2 < XNC) {                   // prefetch c+2 over buf of c-1:
            const float* g = t + ((size_t)(c + 2) * XCH + wv * 4) * ODIM + obase + l * 4;
            float* lp = &tbuf[(c + 2) % 3][(wv * 4) * 256 + l * 4];
            #pragma unroll
            for (int rr = 0; rr < 4; ++rr) async_cp16(g + rr * ODIM, lp + rr * 256);
        }                                    // safe: all waves passed barrier(c)
    }
    relx[(size_t)i * ODIM + obase + tid] = __fsub_rn(1.0f, __fdiv_rn(S, D));
}

// K2: rel_w[b,o] = 1 - S/D, sequential-in-i. Block = o (512 thr = b).
// w-table in LDS; output TRANSPOSED so the store coalesces. (R7, proven.)
__global__ __launch_bounds__(512) void relw_kernel(const float* __restrict__ w,
                                                   const float* __restrict__ t,
                                                   float* __restrict__ relwT) {
    __shared__ XT wtab[IDIM];                // 4 KB
    const int b = threadIdx.x;               // 0..511
    const int o = blockIdx.x;                // 0..511
    if (b < IDIM) {
        float wvv = w[(size_t)b * ODIM + o]; // strided gather, once
        float wc  = __fsub_rn(1.0f, wvv);    // w_comp
        float den = __fsub_rn(1.0f, wc);
        XT e; e.r = 1.0 / (double)den; e.c = wc; e.pad = 0.0f;
        wtab[b] = e;
    }
    float tc = __fsub_rn(1.0f, t[(size_t)b * ODIM + o]);  // strided, once
    __syncthreads();
    float S = 0.0f, D = 0.0f;
    #pragma unroll 8
    for (int i = 0; i < IDIM; ++i) {
        XT e = wtab[i];                      // uniform broadcast b128
        float num = __fsub_rn(tc, e.c);
        float q   = np_min1(q32(num, e.r));
        S = __fadd_rn(S, q);                 // exact sequential order
        D = __fadd_rn(D, e.c);
    }
    relwT[(size_t)o * BDIM + b] = __fsub_rn(1.0f, __fdiv_rn(S, D));  // coalesced
}

// K3: both argmins + gathers. Grid 1024 = (b, oh), 512 thr: waves 0-3 do the
// sx-scan, waves 4-7 the sw-scan (halved serial length). Triple-buffered
// (w,relx) stream, one barrier/chunk, counted vmcnt. 49 KB -> 3 blocks/CU.
#define OCH 8
#define ONC (IDIM / OCH)   // 32
__global__ __launch_bounds__(512) void out_kernel(const float* __restrict__ x,
                                                  const float* __restrict__ w,
                                                  const float* __restrict__ relx,
                                                  const float* __restrict__ relwT,
                                                  float* __restrict__ out) {
    __shared__ float wbuf[3][OCH * 256];     // 24 KB
    __shared__ float rbuf[3][OCH * 256];     // 24 KB
    __shared__ float xrow[IDIM];             // 1 KB
    const int tid  = threadIdx.x;            // 0..511
    const int b    = blockIdx.x >> 1;        // 0..511
    const int obase = (blockIdx.x & 1) * 256;
    const int half = tid >> 8;               // 0: sx duty, 1: sw duty (wave-uniform)
    const int to   = tid & 255;              // o - obase
    const int o    = obase + to;
    const int l = tid & 63, wv = tid >> 6;   // 8 waves

    if (tid < IDIM) xrow[tid] = x[(size_t)b * IDIM + tid];  // coalesced
    float rw = relwT[(size_t)o * BDIM + b];  // gather, 1/thread (sw half uses)
    asm volatile("s_waitcnt vmcnt(0)" ::: "memory");  // rw/x in regs; clean count
    {   // issue chunks 0,1: wave wv stages w-row wv + relx-row wv (2 loads)
        const float* gw0 = w    + (size_t)wv * ODIM + obase + l * 4;
        const float* gr0 = relx + (size_t)wv * ODIM + obase + l * 4;
        async_cp16(gw0, &wbuf[0][wv * 256 + l * 4]);
        async_cp16(gr0, &rbuf[0][wv * 256 + l * 4]);
        const float* gw1 = w    + (size_t)(OCH + wv) * ODIM + obase + l * 4;
        const float* gr1 = relx + (size_t)(OCH + wv) * ODIM + obase + l * 4;
        async_cp16(gw1, &wbuf[1][wv * 256 + l * 4]);
        async_cp16(gr1, &rbuf[1][wv * 256 + l * 4]);
    }
    asm volatile("s_waitcnt lgkmcnt(0)" ::: "memory");  // xrow ds_write done
    __builtin_amdgcn_s_barrier();                       // xrow visible

    float best = (float)INFINITY;            // +INF seed == first-occurrence
    int   idx  = 0;
    for (int c = 0; c < ONC; ++c) {
        if (c == ONC - 1) asm volatile("s_waitcnt vmcnt(0)" ::: "memory");
        else              asm volatile("s_waitcnt vmcnt(2)" ::: "memory");
        __builtin_amdgcn_s_barrier();        // chunk-c rows landed for all
        asm volatile("" ::: "memory");
        if (half == 0) {                     // sx-scan: score(x[b,i], relx[i,o])
            const float* rb = rbuf[c % 3];
            #pragma unroll
            for (int u = 0; u < OCH; ++u) {
                int ii = c * OCH + u;
                float rl = rb[u * 256 + to];     // conflict-free
                float xv = xrow[ii];             // uniform broadcast
                float s  = __fsub_rn(__fadd_rn(xv, rl), __fmul_rn(xv, rl));
                if (np_argmin_better(s, best)) { best = s; idx = ii; }
            }
        } else {                             // sw-scan: score(w[i,o], rw)
            const float* wb = wbuf[c % 3];
            #pragma unroll
            for (int u = 0; u < OCH; ++u) {
                int ii = c * OCH + u;
                float a = wb[u * 256 + to];      // conflict-free
                float s = __fsub_rn(__fadd_rn(a, rw), __fmul_rn(a, rw));
                if (np_argmin_better(s, best)) { best = s; idx = ii; }
            }
        }
        asm volatile("" ::: "memory");
        if (c + 2 < ONC) {                   // prefetch c+2 over buf of c-1
            const float* gw = w    + ((size_t)(c + 2) * OCH + wv) * ODIM + obase + l * 4;
            const float* gr = relx + ((size_t)(c + 2) * OCH + wv) * ODIM + obase + l * 4;
            async_cp16(gw, &wbuf[(c + 2) % 3][wv * 256 + l * 4]);
            async_cp16(gr, &rbuf[(c + 2) % 3][wv * 256 + l * 4]);
        }
    }
    // epilogue: gather + max + store (xrow stable since prologue)
    float cv = fmaxf(xrow[idx], w[(size_t)idx * ODIM + o]);
    out[(size_t)half * BDIM * ODIM + (size_t)b * ODIM + o] = cv;
}

extern "C" void kernel_launch(void* const* d_in, const int* in_sizes, int n_in,
                              void* d_out, int out_size, void* d_ws, size_t ws_size,
                              hipStream_t stream) {
    const float* x = (const float*)d_in[0];  // (B, I)
    const float* w = (const float*)d_in[1];  // (I, O)
    const float* t = (const float*)d_in[2];  // (B, O)
    float* out = (float*)d_out;              // [chosen_x | chosen_w]

    char* ws = (char*)d_ws;
    float* relx  = (float*)(ws);                         // I*O*4 = 512 KB
    float* relwT = (float*)(ws + (IDIM * ODIM * 4));     // O*B*4 = 1 MB

    hipLaunchKernelGGL(relx_kernel, dim3(2 * IDIM), dim3(256), 0, stream, x, t, relx);
    hipLaunchKernelGGL(relw_kernel, dim3(ODIM),     dim3(512), 0, stream, w, t, relwT);
    hipLaunchKernelGGL(out_kernel,  dim3(2 * BDIM), dim3(512), 0, stream, x, w, relx, relwT, out);
}